// Round 1
// baseline (391.029 us; speedup 1.0000x reference)
//
#include <hip/hip_runtime.h>
#include <cstdint>
#include <cstddef>

// Multi-resolution hash grid encoding (Instant-NGP / tcnn style) + progressive mask.
// 16 levels, 2 feats/level, T = 2^19 entries/level, trilinear interp.
// Levels with res^3 <= T are dense grids; others use the tcnn spatial hash.
// mask (d_in[2], 32 floats) gates each output channel; for the benched input
// levels 8..15 are masked to zero, so we skip their gathers entirely (checked
// dynamically against the actual mask values -> correct for any mask).

namespace {

constexpr int      kNLevels = 16;
constexpr uint32_t kT       = 1u << 19;            // 524288 entries per level
constexpr uint32_t kP1      = 2654435761u;          // tcnn hash primes (y, z)
constexpr uint32_t kP2      = 805459861u;

// floor(16 * scale^lv) + 1 with scale = exp((ln 2048 - ln 16)/15)  (numpy doubles)
__device__ constexpr int kRes[kNLevels] = {
    17, 23, 31, 43, 59, 81, 112, 154, 213, 295, 407, 562, 777, 1073, 1483, 2049
};

__global__ __launch_bounds__(256) void hashgrid_encode_kernel(
    const float* __restrict__ x,      // [N, 3]
    const float* __restrict__ table,  // [16, T, 2]
    const float* __restrict__ mask,   // [32]
    float* __restrict__ out,          // [N, 32]
    int n)
{
    const int p = blockIdx.x * blockDim.x + threadIdx.x;
    if (p >= n) return;

    const float px = x[3 * p + 0];
    const float py = x[3 * p + 1];
    const float pz = x[3 * p + 2];

    float4 o[8];

#pragma unroll
    for (int lv = 0; lv < kNLevels; ++lv) {
        const float m0 = mask[2 * lv + 0];
        const float m1 = mask[2 * lv + 1];
        float r0 = 0.0f, r1 = 0.0f;

        if (m0 != 0.0f || m1 != 0.0f) {
            const int  res   = kRes[lv];
            const bool dense = ((long long)res * res * res) <= (long long)kT;
            const float s = (float)(res - 1);

            const float fx = px * s;
            const float fy = py * s;
            const float fz = pz * s;

            int cx = (int)floorf(fx);
            int cy = (int)floorf(fy);
            int cz = (int)floorf(fz);
            cx = min(max(cx, 0), res - 2);
            cy = min(max(cy, 0), res - 2);
            cz = min(max(cz, 0), res - 2);

            const float wx = fx - (float)cx;
            const float wy = fy - (float)cy;
            const float wz = fz - (float)cz;
            const float ux = 1.0f - wx;
            const float uy = 1.0f - wy;
            const float uz = 1.0f - wz;

            const float* __restrict__ tbl = table + (size_t)lv * (size_t)(kT * 2);

            float2 v[8];
            float  w8[8];
#pragma unroll
            for (int c = 0; c < 8; ++c) {
                const int dx = c & 1;
                const int dy = (c >> 1) & 1;
                const int dz = (c >> 2) & 1;
                const int ix = cx + dx;
                const int iy = cy + dy;
                const int iz = cz + dz;
                uint32_t idx;
                if (dense) {
                    idx = (uint32_t)(ix + res * (iy + res * iz));
                } else {
                    idx = (((uint32_t)ix) ^ ((uint32_t)iy * kP1) ^ ((uint32_t)iz * kP2))
                          & (kT - 1u);
                }
                v[c]  = *(const float2*)(tbl + 2u * idx);
                w8[c] = (dx ? wx : ux) * (dy ? wy : uy) * (dz ? wz : uz);
            }
#pragma unroll
            for (int c = 0; c < 8; ++c) {
                r0 = fmaf(v[c].x, w8[c], r0);
                r1 = fmaf(v[c].y, w8[c], r1);
            }
            r0 *= m0;
            r1 *= m1;
        }

        if (lv & 1) {
            o[lv >> 1].z = r0;
            o[lv >> 1].w = r1;
        } else {
            o[lv >> 1].x = r0;
            o[lv >> 1].y = r1;
        }
    }

    float4* __restrict__ op = (float4*)(out + (size_t)p * 32);
#pragma unroll
    for (int i = 0; i < 8; ++i) op[i] = o[i];
}

}  // namespace

extern "C" void kernel_launch(void* const* d_in, const int* in_sizes, int n_in,
                              void* d_out, int out_size, void* d_ws, size_t ws_size,
                              hipStream_t stream) {
    const float* x     = (const float*)d_in[0];
    const float* table = (const float*)d_in[1];
    const float* mask  = (const float*)d_in[2];
    float*       out   = (float*)d_out;

    const int n = in_sizes[0] / 3;  // 1048576 points
    const int block = 256;
    const int grid  = (n + block - 1) / block;
    hashgrid_encode_kernel<<<grid, block, 0, stream>>>(x, table, mask, out, n);
}